// Round 3
// baseline (111.824 us; speedup 1.0000x reference)
//
#include <hip/hip_runtime.h>

// Problem constants (match reference)
#define TP_DIM 8
#define TOKENS 2048
#define HIDDEN 7168
#define EPS_F 0.0078125f

constexpr int THREADS    = 256;
constexpr int V4_PER_ROW = HIDDEN / 4;            // 1792 float4 per row
constexpr int CHUNKS     = V4_PER_ROW / THREADS;  // 7 float4 per thread

using f32x4 = __attribute__((ext_vector_type(4))) float;

__global__ __launch_bounds__(THREADS)
void ar_rmsnorm_kernel(const float* __restrict__ x,
                       const float* __restrict__ residual_in,
                       const float* __restrict__ gamma,
                       float* __restrict__ normed,
                       float* __restrict__ residual_out)
{
    const int t   = blockIdx.x;          // token row
    const int tid = threadIdx.x;

    const size_t rowOff   = (size_t)t * V4_PER_ROW;          // in float4 units
    const size_t tpStride = (size_t)TOKENS * V4_PER_ROW;     // slice stride, float4 units

    const f32x4* __restrict__ xv = (const f32x4*)x + rowOff;
    const f32x4* __restrict__ rv = (const f32x4*)residual_in + rowOff;
    const f32x4* __restrict__ gv = (const f32x4*)gamma;
    f32x4* __restrict__ nv = (f32x4*)normed + rowOff;
    f32x4* __restrict__ ov = (f32x4*)residual_out + rowOff;

    f32x4 acc[CHUNKS];
    float ssq = 0.0f;

    // Pure-read phase: all 9 streams, no interleaved writes (avoid HBM
    // read/write turnaround; writes are clustered in the epilogue).
    #pragma unroll
    for (int c = 0; c < CHUNKS; ++c) {
        const int col = c * THREADS + tid;
        f32x4 a = __builtin_nontemporal_load(&rv[col]);
        #pragma unroll
        for (int p = 0; p < TP_DIM; ++p) {
            f32x4 v = __builtin_nontemporal_load(&xv[(size_t)p * tpStride + col]);
            a += v;
        }
        acc[c] = a;
        ssq += a.x * a.x + a.y * a.y + a.z * a.z + a.w * a.w;
    }

    // Wave (64-lane) butterfly reduction of sum-of-squares
    #pragma unroll
    for (int off = 1; off < 64; off <<= 1)
        ssq += __shfl_xor(ssq, off, 64);

    // Cross-wave via LDS (4 waves/block)
    __shared__ float wsum[THREADS / 64];
    const int wave = tid >> 6;
    if ((tid & 63) == 0) wsum[wave] = ssq;
    __syncthreads();
    float total = wsum[0] + wsum[1] + wsum[2] + wsum[3];

    const float scale = rsqrtf(total * (1.0f / (float)HIDDEN) + EPS_F);

    // Write phase: both outputs, clustered.
    #pragma unroll
    for (int c = 0; c < CHUNKS; ++c) {
        const int col = c * THREADS + tid;
        f32x4 g = gv[col];          // gamma is reused by all blocks: keep cached
        f32x4 a = acc[c];
        __builtin_nontemporal_store(a, &ov[col]);
        f32x4 o = a * scale * g;
        __builtin_nontemporal_store(o, &nv[col]);
    }
}

extern "C" void kernel_launch(void* const* d_in, const int* in_sizes, int n_in,
                              void* d_out, int out_size, void* d_ws, size_t ws_size,
                              hipStream_t stream) {
    const float* x           = (const float*)d_in[0];   // [8][2048][7168]
    const float* residual_in = (const float*)d_in[1];   // [2048][7168]
    const float* gamma       = (const float*)d_in[2];   // [7168]

    float* normed       = (float*)d_out;                              // [2048][7168]
    float* residual_out = (float*)d_out + (size_t)TOKENS * HIDDEN;    // [2048][7168]

    dim3 grid(TOKENS);
    dim3 block(THREADS);
    ar_rmsnorm_kernel<<<grid, block, 0, stream>>>(x, residual_in, gamma,
                                                  normed, residual_out);
}

// Round 4
// 107.074 us; speedup vs baseline: 1.0444x; 1.0444x over previous
//
#include <hip/hip_runtime.h>

// Problem constants (match reference)
#define TP_DIM 8
#define TOKENS 2048
#define HIDDEN 7168
#define EPS_F 0.0078125f

constexpr int THREADS    = 256;
constexpr int V4_PER_ROW = HIDDEN / 4;            // 1792 float4 per row
constexpr int CHUNKS     = V4_PER_ROW / THREADS;  // 7 float4 per thread

using f32x4 = __attribute__((ext_vector_type(4))) float;

__global__ __launch_bounds__(THREADS)
void ar_rmsnorm_kernel(const float* __restrict__ x,
                       const float* __restrict__ residual_in,
                       const float* __restrict__ gamma,
                       float* __restrict__ normed,
                       float* __restrict__ residual_out)
{
    const int t   = blockIdx.x;          // token row
    const int tid = threadIdx.x;

    const size_t rowOff   = (size_t)t * V4_PER_ROW;          // in float4 units
    const size_t tpStride = (size_t)TOKENS * V4_PER_ROW;     // slice stride, float4 units

    const f32x4* __restrict__ xv = (const f32x4*)x + rowOff;
    const f32x4* __restrict__ rv = (const f32x4*)residual_in + rowOff;
    const f32x4* __restrict__ gv = (const f32x4*)gamma;
    f32x4* __restrict__ nv = (f32x4*)normed + rowOff;
    f32x4* __restrict__ ov = (f32x4*)residual_out + rowOff;

    f32x4 acc[CHUNKS];

    // Slice-major read order: 7 contiguous chunk-loads from ONE stream
    // before switching streams -> longer same-DRAM-page bursts than the
    // chunk-major order (which alternated between 9 streams 58.7MB apart).
    #pragma unroll
    for (int c = 0; c < CHUNKS; ++c)
        acc[c] = __builtin_nontemporal_load(&rv[c * THREADS + tid]);

    #pragma unroll
    for (int p = 0; p < TP_DIM; ++p) {
        const f32x4* __restrict__ xp = xv + (size_t)p * tpStride;
        #pragma unroll
        for (int c = 0; c < CHUNKS; ++c)
            acc[c] += __builtin_nontemporal_load(&xp[c * THREADS + tid]);
    }

    float ssq = 0.0f;
    #pragma unroll
    for (int c = 0; c < CHUNKS; ++c) {
        f32x4 a = acc[c];
        ssq += a.x * a.x + a.y * a.y + a.z * a.z + a.w * a.w;
        __builtin_nontemporal_store(a, &ov[c * THREADS + tid]);
    }

    // Wave (64-lane) butterfly reduction of sum-of-squares
    #pragma unroll
    for (int off = 1; off < 64; off <<= 1)
        ssq += __shfl_xor(ssq, off, 64);

    // Cross-wave via LDS (4 waves/block)
    __shared__ float wsum[THREADS / 64];
    const int wave = tid >> 6;
    if ((tid & 63) == 0) wsum[wave] = ssq;
    __syncthreads();
    float total = wsum[0] + wsum[1] + wsum[2] + wsum[3];

    const float scale = rsqrtf(total * (1.0f / (float)HIDDEN) + EPS_F);

    #pragma unroll
    for (int c = 0; c < CHUNKS; ++c) {
        const int col = c * THREADS + tid;
        f32x4 g = gv[col];          // gamma is reused by all blocks: keep cached
        f32x4 o = acc[c] * scale * g;
        __builtin_nontemporal_store(o, &nv[col]);
    }
}

extern "C" void kernel_launch(void* const* d_in, const int* in_sizes, int n_in,
                              void* d_out, int out_size, void* d_ws, size_t ws_size,
                              hipStream_t stream) {
    const float* x           = (const float*)d_in[0];   // [8][2048][7168]
    const float* residual_in = (const float*)d_in[1];   // [2048][7168]
    const float* gamma       = (const float*)d_in[2];   // [7168]

    float* normed       = (float*)d_out;                              // [2048][7168]
    float* residual_out = (float*)d_out + (size_t)TOKENS * HIDDEN;    // [2048][7168]

    dim3 grid(TOKENS);
    dim3 block(THREADS);
    ar_rmsnorm_kernel<<<grid, block, 0, stream>>>(x, residual_in, gamma,
                                                  normed, residual_out);
}